// Round 7
// baseline (11114.515 us; speedup 1.0000x reference)
//
#include <hip/hip_runtime.h>
#include <hip/hip_bf16.h>

// RecurrentAE on MI355X — round 7.
//  - r6 structure unchanged (write-once h ring -> zero per-step cache maintenance;
//    128 WGs x 512 thr; weights LDS-resident; stride-1036 conflict-free LDS; tp4
//    in-register gate epilogue; permuted contiguous u32 h-stores; fused out N-tile).
//  - ONLY change: barrier detection. r6 polled a 16-line sum with serialized atomic
//    loads (~16 x 600cyc LLC RTs per round = the hidden 6 us/step). Now: 16 sub-lines
//    (8 WGs each, RMW-parallel) -> 8th arriver bumps ONE root line -> everyone polls
//    the single root (1 load/round).

#define B_ 128
#define S_ 512
#define NWG 128
#define THR 512
#define WSTR 1036       // LDS row stride (elems): 518 dw == 6 mod 32 -> conflict-free b64
#define XSTR 140        // 70 dw == 6 mod 32
#define SLOT 131072     // bf16 elems per ring slot (128 rows x 1024)

typedef __bf16 bf16x8 __attribute__((ext_vector_type(8)));
typedef float  f32x4  __attribute__((ext_vector_type(4)));
typedef unsigned long long u64;

union pk2 { unsigned u; __bf16 h[2]; };
union b8u { u64 q[2]; bf16x8 v; };

// ---------------- workspace layout (bytes) ----------------
#define O_RING 0
#define RING_BYTES (513ull * 262144ull)      // 134,479,872
#define O_H32  ((size_t)RING_BYTES)          // f32 [128][1024]
#define O_CTR  (O_H32 + 524288)              // enc 4 KB @ +0, dec 4 KB @ +4096
#define O_XB   (O_CTR + 8192)                // bf16 [128][512*128] = 16 MB
#define O_WEH  (O_XB  + 16777216)            // bf16 [128][2][16][1024] = 8 MB
#define O_WEX  (O_WEH + 8388608)             // bf16 [128][2][16][128]  = 1 MB
#define O_BE   (O_WEX + 1048576)             // f32  [128][32]
#define O_WD   (O_BE  + 16384)               // bf16 [128][2][16][1024] = 8 MB
#define O_BD   (O_WD  + 8388608)             // f32  [128][32]
#define O_WO   (O_BD  + 16384)               // bf16 [8][16][1024] = 256 KB
#define O_BO   (O_WO  + 262144)              // f32  [8][16]
#define O_WC   (O_BO  + 512)                 // bf16 [3072][1024] = 6 MB (prep scratch)
// total ~176 MB

// stored-h column permutation within each 8-unit block: [u0,u4,u1,u5,u2,u6,u3,u7]
__device__ __host__ inline int permk(int k) { return (k & ~7) + (k & 1) * 4 + ((k >> 1) & 3); }

// ---------------- prep kernels (validated r5/r6) ----------------

__global__ void k_xcvt(const float* __restrict__ x, __bf16* __restrict__ xb, int n) {
    int i = blockIdx.x * 256 + threadIdx.x;
    int stride = gridDim.x * 256;
    for (; i < n; i += stride) xb[i] = (__bf16)x[i];
}

__global__ void k_pack_enc(const float* __restrict__ Wih, const float* __restrict__ Whh,
                           const float* __restrict__ bih, const float* __restrict__ bhh,
                           __bf16* __restrict__ Weh, __bf16* __restrict__ Wex,
                           float* __restrict__ be) {
    int g = blockIdx.x, tid = threadIdx.x;
    for (int i = tid; i < 2 * 16 * 1024; i += 256) {
        int t = i >> 14, rem = i & 16383, tc = rem >> 10, k = rem & 1023;
        int u = g * 8 + t * 4 + (tc >> 2), gate = tc & 3;
        int o = permk(k);
        float v = 0.f;
        if (gate == 0)      v = Whh[(size_t)u * 1024 + o];
        else if (gate == 1) v = Whh[(size_t)(1024 + u) * 1024 + o];
        else if (gate == 3) v = Whh[(size_t)(2048 + u) * 1024 + o];
        Weh[((size_t)(g * 2 + t) * 16 + tc) * 1024 + k] = (__bf16)v;
    }
    for (int i = tid; i < 2 * 16 * 128; i += 256) {
        int t = i >> 11, rem = i & 2047, tc = rem >> 7, k = rem & 127;
        int u = g * 8 + t * 4 + (tc >> 2), gate = tc & 3;
        float v = 0.f;
        if (gate == 0)      v = Wih[(size_t)u * 128 + k];
        else if (gate == 1) v = Wih[(size_t)(1024 + u) * 128 + k];
        else if (gate == 2) v = Wih[(size_t)(2048 + u) * 128 + k];
        Wex[((size_t)(g * 2 + t) * 16 + tc) * 128 + k] = (__bf16)v;
    }
    if (tid < 32) {
        int c = tid, u = g * 8 + (c >> 4) * 4 + ((c >> 2) & 3), gate = c & 3;
        float v;
        if (gate == 0)      v = bih[u] + bhh[u];
        else if (gate == 1) v = bih[1024 + u] + bhh[1024 + u];
        else if (gate == 2) v = bih[2048 + u];
        else                v = bhh[2048 + u];
        be[g * 32 + c] = v;
    }
}

__global__ void k_wcomb(const float* __restrict__ Wihd, const float* __restrict__ Wout,
                        __bf16* __restrict__ Wc) {
    __shared__ float a[8][128];
    int r0 = blockIdx.x * 8, tid = threadIdx.x;
    for (int i = tid; i < 8 * 128; i += 256)
        a[i >> 7][i & 127] = Wihd[(size_t)(r0 + (i >> 7)) * 128 + (i & 127)];
    __syncthreads();
    for (int j = tid; j < 1024; j += 256) {
        float acc[8] = {0, 0, 0, 0, 0, 0, 0, 0};
        for (int f = 0; f < 128; ++f) {
            float w = Wout[(size_t)f * 1024 + j];
#pragma unroll
            for (int r = 0; r < 8; ++r) acc[r] += a[r][f] * w;
        }
        for (int r = 0; r < 8; ++r) Wc[(size_t)(r0 + r) * 1024 + j] = (__bf16)acc[r];
    }
}

__global__ void k_pack_dec(const float* __restrict__ Whhd, const __bf16* __restrict__ Wc,
                           const float* __restrict__ Wihd, const float* __restrict__ bihd,
                           const float* __restrict__ bhhd, const float* __restrict__ bout,
                           __bf16* __restrict__ Wd, float* __restrict__ bd) {
    int g = blockIdx.x, tid = threadIdx.x;
    for (int i = tid; i < 2 * 16 * 1024; i += 256) {
        int t = i >> 14, rem = i & 16383, tc = rem >> 10, k = rem & 1023;
        int u = g * 8 + t * 4 + (tc >> 2), gate = tc & 3;
        int o = permk(k);
        float v;
        if (gate == 0)      v = Whhd[(size_t)u * 1024 + o] + (float)Wc[(size_t)u * 1024 + o];
        else if (gate == 1) v = Whhd[(size_t)(1024 + u) * 1024 + o] + (float)Wc[(size_t)(1024 + u) * 1024 + o];
        else if (gate == 2) v = (float)Wc[(size_t)(2048 + u) * 1024 + o];
        else                v = Whhd[(size_t)(2048 + u) * 1024 + o];
        Wd[((size_t)(g * 2 + t) * 16 + tc) * 1024 + k] = (__bf16)v;
    }
    if (tid < 32) {
        int c = tid, u = g * 8 + (c >> 4) * 4 + ((c >> 2) & 3), gate = c & 3;
        int row = (gate == 0) ? u : (gate == 1) ? (1024 + u) : (2048 + u);
        float v;
        if (gate <= 2) {
            float d = 0.f;
            for (int f = 0; f < 128; ++f) d += Wihd[(size_t)row * 128 + f] * bout[f];
            v = d + bihd[row] + ((gate <= 1) ? bhhd[row] : 0.f);
        } else {
            v = bhhd[row];
        }
        bd[g * 32 + c] = v;
    }
}

__global__ void k_pack_out(const float* __restrict__ Wout, const float* __restrict__ bout,
                           __bf16* __restrict__ Wo, float* __restrict__ bo) {
    int og = blockIdx.x, tid = threadIdx.x;
    for (int i = tid; i < 16 * 1024; i += 256) {
        int fl = i >> 10, k = i & 1023;
        Wo[((size_t)og * 16 + fl) * 1024 + k] = (__bf16)Wout[(size_t)(og * 16 + fl) * 1024 + permk(k)];
    }
    if (tid < 16) bo[og * 16 + tid] = bout[og * 16 + tid];
}

// ---------------- two-level barrier with single-root detection ----------------
// ctr (u32 idx): subs j*32 (j<16, 128B apart); root at idx 512 (own line).
// Arrive: RMW own sub-line (8 WGs/line -> parallel); 8th arriver of group bumps root.
// Wait: poll ONE root line (root >= 16*step). No fences anywhere (write-once ring).
__device__ __forceinline__ void bar_arrive(unsigned* c, int g, unsigned step1) {
    if (threadIdx.x == 0) {
        unsigned old = __hip_atomic_fetch_add(c + (g & 15) * 32, 1u,
                                              __ATOMIC_RELAXED, __HIP_MEMORY_SCOPE_AGENT);
        if (old == step1 * 8u - 1u)
            __hip_atomic_fetch_add(c + 512, 1u, __ATOMIC_RELAXED, __HIP_MEMORY_SCOPE_AGENT);
    }
}
__device__ __forceinline__ void bar_wait(unsigned* c, unsigned step1) {
    if (threadIdx.x == 0) {
        while (__hip_atomic_load(c + 512, __ATOMIC_RELAXED, __HIP_MEMORY_SCOPE_AGENT) < step1 * 16u)
            __builtin_amdgcn_s_sleep(1);
    }
    __syncthreads();
}

#define MFMA16(a, b, c) __builtin_amdgcn_mfma_f32_16x16x32_bf16(a, b, c, 0, 0, 0)

// ---------------- encoder ----------------
__global__ __launch_bounds__(THR, 1) void k_enc(
    const __bf16* __restrict__ xb, const __bf16* __restrict__ Weh,
    const __bf16* __restrict__ Wex, const float* __restrict__ be,
    __bf16* __restrict__ ring, float* __restrict__ h32, unsigned* __restrict__ ctr) {
    __shared__ __bf16 sWh[2][16][WSTR];
    __shared__ __bf16 sWx[2][16][XSTR];
    const int g = blockIdx.x, tid = threadIdx.x;
    const int lane = tid & 63, wv = tid >> 6;
    const int tcol = lane & 15, quad = lane >> 4, kq = quad * 8;
    const int q = tcol >> 2, jr = tcol & 3;

    for (int i = tid; i < 8192; i += THR) {
        int t = i >> 12, rem = i & 4095, tc = rem >> 8, k4 = rem & 255;
        *(u64*)&sWh[t][tc][k4 * 4] = *(const u64*)(Weh + ((size_t)(g * 2 + t) * 16 + tc) * 1024 + k4 * 4);
    }
    for (int i = tid; i < 1024; i += THR) {
        int t = i >> 9, rem = i & 511, tc = rem >> 5, k4 = rem & 31;
        *(u64*)&sWx[t][tc][k4 * 4] = *(const u64*)(Wex + ((size_t)(g * 2 + t) * 16 + tc) * 128 + k4 * 4);
    }
    float bR[2], bZ[2], bNI[2], bNH[2];
#pragma unroll
    for (int t = 0; t < 2; ++t) {
        int cb = g * 32 + t * 16 + (tcol & 12);
        bR[t] = be[cb]; bZ[t] = be[cb + 1]; bNI[t] = be[cb + 2]; bNH[t] = be[cb + 3];
    }
    __syncthreads();

    const int rowA = wv * 16 + tcol;
    const int rowE = wv * 16 + 4 * quad + jr;
    float hprev[2] = {0.f, 0.f};
    f32x4 acc[2];

    auto ldsb = [&](int t, int kt) -> bf16x8 {
        b8u u;
        const __bf16* p = &sWh[t][tcol][kt * 32 + kq];
        u.q[0] = *(const u64*)p; u.q[1] = *(const u64*)(p + 4);
        return u.v;
    };
    auto xwin = [&](int s) {
        acc[0] = f32x4{0, 0, 0, 0}; acc[1] = f32x4{0, 0, 0, 0};
#pragma unroll
        for (int kt = 0; kt < 4; ++kt) {
            b8u b0, b1;
            const __bf16* p0 = &sWx[0][tcol][kt * 32 + kq];
            const __bf16* p1 = &sWx[1][tcol][kt * 32 + kq];
            b0.q[0] = *(const u64*)p0; b0.q[1] = *(const u64*)(p0 + 4);
            b1.q[0] = *(const u64*)p1; b1.q[1] = *(const u64*)(p1 + 4);
            bf16x8 a = *(const bf16x8*)(xb + (size_t)rowA * 65536 + s * 128 + kt * 32 + kq);
            acc[0] = MFMA16(a, b0.v, acc[0]);
            acc[1] = MFMA16(a, b1.v, acc[1]);
        }
    };
    auto tp4 = [&](f32x4& a) {
        bool s0 = tcol & 1, s1 = tcol & 2;
        float v;
        v = __shfl_xor(s0 ? a[0] : a[1], 1); if (s0) a[0] = v; else a[1] = v;
        v = __shfl_xor(s0 ? a[2] : a[3], 1); if (s0) a[2] = v; else a[3] = v;
        v = __shfl_xor(s1 ? a[0] : a[2], 2); if (s1) a[0] = v; else a[2] = v;
        v = __shfl_xor(s1 ? a[1] : a[3], 2); if (s1) a[1] = v; else a[3] = v;
    };

    xwin(0);
    for (int s = 0; s < 512; ++s) {
        const __bf16* hc = ring + (size_t)s * SLOT;
        unsigned* hn = (unsigned*)ring + (size_t)(s + 1) * (SLOT / 2);
#pragma unroll 8
        for (int kt = 0; kt < 32; ++kt) {
            bf16x8 b0 = ldsb(0, kt), b1 = ldsb(1, kt);
            bf16x8 a = *(const bf16x8*)(hc + (size_t)rowA * 1024 + kt * 32 + kq);
            acc[0] = MFMA16(a, b0, acc[0]);
            acc[1] = MFMA16(a, b1, acc[1]);
        }
        tp4(acc[0]); tp4(acc[1]);
        pk2 p;
#pragma unroll
        for (int t = 0; t < 2; ++t) {
            float r = 1.f / (1.f + __expf(-(acc[t][0] + bR[t])));
            float z = 1.f / (1.f + __expf(-(acc[t][1] + bZ[t])));
            float n = tanhf(acc[t][2] + bNI[t] + r * (acc[t][3] + bNH[t]));
            float h = (1.f - z) * n + z * hprev[t];
            hprev[t] = h;
            p.h[t] = (__bf16)h;
        }
        __hip_atomic_store(hn + rowE * 512 + g * 4 + q, p.u,
                           __ATOMIC_RELAXED, __HIP_MEMORY_SCOPE_AGENT);
        if (s == 511) {
#pragma unroll
            for (int t = 0; t < 2; ++t)
                __hip_atomic_store(h32 + rowE * 1024 + g * 8 + q * 2 + t, hprev[t],
                                   __ATOMIC_RELAXED, __HIP_MEMORY_SCOPE_AGENT);
        }
        if (s < 511) {
            __syncthreads();             // drains write-through h stores (vmcnt 0)
            bar_arrive(ctr, g, (unsigned)(s + 1));
            xwin(s + 1);                 // overlap next x-GEMM with grid convergence
            bar_wait(ctr, (unsigned)(s + 1));
        }
    }
}

// ---------------- decoder ----------------
__global__ __launch_bounds__(THR, 1) void k_dec(
    const __bf16* __restrict__ Wd, const float* __restrict__ bd,
    const __bf16* __restrict__ Wo, const float* __restrict__ bo,
    __bf16* __restrict__ ring, const float* __restrict__ h32,
    float* __restrict__ out, unsigned* __restrict__ ctr) {
    __shared__ __bf16 sWh[2][16][WSTR];
    __shared__ __bf16 sWo[16][WSTR];
    const int g = blockIdx.x, tid = threadIdx.x;
    const int lane = tid & 63, wv = tid >> 6;
    const int tcol = lane & 15, quad = lane >> 4, kq = quad * 8;
    const int q = tcol >> 2, jr = tcol & 3;
    const bool has_out = (g < 8);

    for (int i = tid; i < 8192; i += THR) {
        int t = i >> 12, rem = i & 4095, tc = rem >> 8, k4 = rem & 255;
        *(u64*)&sWh[t][tc][k4 * 4] = *(const u64*)(Wd + ((size_t)(g * 2 + t) * 16 + tc) * 1024 + k4 * 4);
    }
    if (has_out) {
        for (int i = tid; i < 4096; i += THR) {
            int tc = i >> 8, k4 = i & 255;
            *(u64*)&sWo[tc][k4 * 4] = *(const u64*)(Wo + ((size_t)g * 16 + tc) * 1024 + k4 * 4);
        }
    }
    float bR[2], bZ[2], bNI[2], bNH[2];
#pragma unroll
    for (int t = 0; t < 2; ++t) {
        int cb = g * 32 + t * 16 + (tcol & 12);
        bR[t] = bd[cb]; bZ[t] = bd[cb + 1]; bNI[t] = bd[cb + 2]; bNH[t] = bd[cb + 3];
    }
    const float bo_v = has_out ? bo[g * 16 + tcol] : 0.f;

    const int rowA = wv * 16 + tcol;
    const int rowE = wv * 16 + 4 * quad + jr;
    float hprev[2];
#pragma unroll
    for (int t = 0; t < 2; ++t)
        hprev[t] = h32[rowE * 1024 + g * 8 + q * 2 + t];
    __syncthreads();

    auto ldsb = [&](const __bf16* p) -> bf16x8 {
        b8u u;
        u.q[0] = *(const u64*)p; u.q[1] = *(const u64*)(p + 4);
        return u.v;
    };
    auto tp4 = [&](f32x4& a) {
        bool s0 = tcol & 1, s1 = tcol & 2;
        float v;
        v = __shfl_xor(s0 ? a[0] : a[1], 1); if (s0) a[0] = v; else a[1] = v;
        v = __shfl_xor(s0 ? a[2] : a[3], 1); if (s0) a[2] = v; else a[3] = v;
        v = __shfl_xor(s1 ? a[0] : a[2], 2); if (s1) a[0] = v; else a[2] = v;
        v = __shfl_xor(s1 ? a[1] : a[3], 2); if (s1) a[1] = v; else a[3] = v;
    };

    for (int s = 0; s < 512; ++s) {
        const int rd = s ? (s - 1) : 512;
        const __bf16* hc = ring + (size_t)rd * SLOT;
        unsigned* hn = (unsigned*)ring + (size_t)s * (SLOT / 2);
        f32x4 acc0 = {0, 0, 0, 0}, acc1 = {0, 0, 0, 0}, acc2 = {0, 0, 0, 0};
#pragma unroll 8
        for (int kt = 0; kt < 32; ++kt) {
            bf16x8 b0 = ldsb(&sWh[0][tcol][kt * 32 + kq]);
            bf16x8 b1 = ldsb(&sWh[1][tcol][kt * 32 + kq]);
            bf16x8 a = *(const bf16x8*)(hc + (size_t)rowA * 1024 + kt * 32 + kq);
            acc0 = MFMA16(a, b0, acc0);
            acc1 = MFMA16(a, b1, acc1);
            if (has_out) acc2 = MFMA16(a, ldsb(&sWo[tcol][kt * 32 + kq]), acc2);
        }
        if (has_out && s >= 1) {
#pragma unroll
            for (int i = 0; i < 4; ++i) {
                int row = wv * 16 + quad * 4 + i;
                out[(size_t)row * 65536 + (size_t)(512 - s) * 128 + g * 16 + tcol] = acc2[i] + bo_v;
            }
        }
        tp4(acc0); tp4(acc1);
        f32x4 ac[2] = {acc0, acc1};
        pk2 p;
#pragma unroll
        for (int t = 0; t < 2; ++t) {
            float r = 1.f / (1.f + __expf(-(ac[t][0] + bR[t])));
            float z = 1.f / (1.f + __expf(-(ac[t][1] + bZ[t])));
            float n = tanhf(ac[t][2] + bNI[t] + r * (ac[t][3] + bNH[t]));
            float h = (1.f - z) * n + z * hprev[t];
            hprev[t] = h;
            p.h[t] = (__bf16)h;
        }
        __hip_atomic_store(hn + rowE * 512 + g * 4 + q, p.u,
                           __ATOMIC_RELAXED, __HIP_MEMORY_SCOPE_AGENT);
        __syncthreads();
        bar_arrive(ctr, g, (unsigned)(s + 1));
        if (s < 511) bar_wait(ctr, (unsigned)(s + 1));
    }
    // final out pass: out[:, 0, :] = W_out h^d_512 + b_out (slot 511)
    if (has_out) {
        bar_wait(ctr, 512u);
        const __bf16* hc = ring + (size_t)511 * SLOT;
        f32x4 acc2 = {0, 0, 0, 0};
#pragma unroll 8
        for (int kt = 0; kt < 32; ++kt) {
            bf16x8 a = *(const bf16x8*)(hc + (size_t)rowA * 1024 + kt * 32 + kq);
            acc2 = MFMA16(a, ldsb(&sWo[tcol][kt * 32 + kq]), acc2);
        }
#pragma unroll
        for (int i = 0; i < 4; ++i) {
            int row = wv * 16 + quad * 4 + i;
            out[(size_t)row * 65536 + g * 16 + tcol] = acc2[i] + bo_v;
        }
    }
}

// ---------------- launch ----------------
extern "C" void kernel_launch(void* const* d_in, const int* in_sizes, int n_in,
                              void* d_out, int out_size, void* d_ws, size_t ws_size,
                              hipStream_t stream) {
    (void)in_sizes; (void)n_in; (void)out_size; (void)ws_size;
    const float* x    = (const float*)d_in[0];
    const float* Wihe = (const float*)d_in[1];
    const float* Whhe = (const float*)d_in[2];
    const float* bihe = (const float*)d_in[3];
    const float* bhhe = (const float*)d_in[4];
    const float* Wihd = (const float*)d_in[5];
    const float* Whhd = (const float*)d_in[6];
    const float* bihd = (const float*)d_in[7];
    const float* bhhd = (const float*)d_in[8];
    const float* Wout = (const float*)d_in[9];
    const float* bout = (const float*)d_in[10];

    char* ws = (char*)d_ws;
    __bf16*   ring = (__bf16*)(ws + O_RING);
    float*    h32  = (float*)(ws + O_H32);
    unsigned* ctr  = (unsigned*)(ws + O_CTR);
    __bf16*   xbf  = (__bf16*)(ws + O_XB);
    __bf16*   Weh  = (__bf16*)(ws + O_WEH);
    __bf16*   Wex  = (__bf16*)(ws + O_WEX);
    float*    be   = (float*)(ws + O_BE);
    __bf16*   Wd   = (__bf16*)(ws + O_WD);
    float*    bd   = (float*)(ws + O_BD);
    __bf16*   Wo   = (__bf16*)(ws + O_WO);
    float*    bo   = (float*)(ws + O_BO);
    __bf16*   Wc   = (__bf16*)(ws + O_WC);

    hipMemsetAsync(ring, 0, 262144, stream);         // slot 0 = h_0 = 0
    hipMemsetAsync(ctr, 0, 8192, stream);            // barrier counters

    k_xcvt<<<4096, 256, 0, stream>>>(x, xbf, B_ * S_ * 128);
    k_pack_enc<<<NWG, 256, 0, stream>>>(Wihe, Whhe, bihe, bhhe, Weh, Wex, be);
    k_wcomb<<<384, 256, 0, stream>>>(Wihd, Wout, Wc);
    k_pack_dec<<<NWG, 256, 0, stream>>>(Whhd, Wc, Wihd, bihd, bhhd, bout, Wd, bd);
    k_pack_out<<<8, 256, 0, stream>>>(Wout, bout, Wo, bo);

    k_enc<<<NWG, THR, 0, stream>>>(xbf, Weh, Wex, be, ring, h32, ctr);
    k_dec<<<NWG, THR, 0, stream>>>(Wd, bd, Wo, bo, ring, h32, (float*)d_out, ctr + 1024);
}